// Round 1
// baseline (674.421 us; speedup 1.0000x reference)
//
#include <hip/hip_runtime.h>

// Problem constants (match reference setup_inputs()).
#define N_NODES 20000
#define E_EDGES 640000
// Layer dims: IN=256, H=8, HF=64, OUT=32

// ---------------------------------------------------------------------------
// CSR build: deg init (self-loop counts as 1), count, scan, scatter
// ---------------------------------------------------------------------------
__global__ __launch_bounds__(256) void init_deg_kernel(int* __restrict__ deg, int n) {
    int i = blockIdx.x * 256 + threadIdx.x;
    if (i < n) deg[i] = 1;  // every node gets exactly one self-loop
}

__global__ __launch_bounds__(256) void count_deg_kernel(const int* __restrict__ ei, int e,
                                                        int* __restrict__ deg) {
    int i = blockIdx.x * 256 + threadIdx.x;
    if (i < e) atomicAdd(&deg[ei[e + i]], 1);  // ei[1][i] = dst
}

__global__ __launch_bounds__(1024) void scan_kernel(const int* __restrict__ deg,
                                                    int* __restrict__ row_start,
                                                    int* __restrict__ cursor, int n) {
    __shared__ int wsum[16];
    __shared__ int carry_s;
    const int t = threadIdx.x;
    const int lane = t & 63;
    const int wv = t >> 6;
    int running = 0;
    for (int base = 0; base < n; base += 1024) {
        int idx = base + t;
        int v = (idx < n) ? deg[idx] : 0;
        // wave-level inclusive scan (64 lanes)
        int x = v;
        #pragma unroll
        for (int off = 1; off < 64; off <<= 1) {
            int y = __shfl_up(x, off, 64);
            if (lane >= off) x += y;
        }
        if (lane == 63) wsum[wv] = x;
        __syncthreads();
        if (wv == 0 && lane < 16) {
            int w = wsum[lane];
            int xx = w;
            #pragma unroll
            for (int off = 1; off < 16; off <<= 1) {
                int y = __shfl_up(xx, off, 64);
                if (lane >= off) xx += y;
            }
            wsum[lane] = xx - w;          // exclusive wave offset
            if (lane == 15) carry_s = xx; // chunk total
        }
        __syncthreads();
        int excl = running + wsum[wv] + (x - v);
        if (idx < n) { row_start[idx] = excl; cursor[idx] = excl; }
        running += carry_s;
        __syncthreads();
    }
    if (t == 0) row_start[n] = running;
}

__global__ __launch_bounds__(256) void scatter_kernel(const int* __restrict__ ei, int e, int n,
                                                      int* __restrict__ cursor,
                                                      int* __restrict__ csr_src) {
    int i = blockIdx.x * 256 + threadIdx.x;
    if (i >= e + n) return;
    int s, d;
    if (i < e) { s = ei[i]; d = ei[e + i]; }
    else       { s = i - e; d = s; }       // self-loop
    int slot = atomicAdd(&cursor[d], 1);
    csr_src[slot] = s;
}

// ---------------------------------------------------------------------------
// fp32 tiled GEMM: C[M,N] = A[M,K] @ B[K,N].  K % 16 == 0, N % 64 == 0.
// 64x64 block tile, 256 threads, 4x4 micro-tile.
// ---------------------------------------------------------------------------
__global__ __launch_bounds__(256) void gemm_kernel(const float* __restrict__ A,
                                                   const float* __restrict__ B,
                                                   float* __restrict__ C,
                                                   int M, int K, int N) {
    __shared__ float As[16][68];  // [k][m], padded to break 4-way write conflicts
    __shared__ float Bs[16][64];  // [k][n]
    const int t = threadIdx.x;
    const int bm = blockIdx.x * 64;
    const int bn = blockIdx.y * 64;
    const int tx = t & 15, ty = t >> 4;
    const int arow = t >> 2;          // 0..63
    const int acol4 = (t & 3) * 4;    // 0,4,8,12
    const int brow = t >> 4;          // 0..15
    const int bcol4 = (t & 15) * 4;

    float acc[4][4];
    #pragma unroll
    for (int i = 0; i < 4; ++i)
        #pragma unroll
        for (int j = 0; j < 4; ++j) acc[i][j] = 0.f;

    for (int k0 = 0; k0 < K; k0 += 16) {
        float4 av;
        if (bm + arow < M) av = *(const float4*)&A[(size_t)(bm + arow) * K + k0 + acol4];
        else               av = make_float4(0.f, 0.f, 0.f, 0.f);
        float4 bv = *(const float4*)&B[(size_t)(k0 + brow) * N + bn + bcol4];
        As[acol4 + 0][arow] = av.x;
        As[acol4 + 1][arow] = av.y;
        As[acol4 + 2][arow] = av.z;
        As[acol4 + 3][arow] = av.w;
        *(float4*)&Bs[brow][bcol4] = bv;
        __syncthreads();
        #pragma unroll
        for (int kk = 0; kk < 16; ++kk) {
            float4 a = *(const float4*)&As[kk][ty * 4];
            float4 b = *(const float4*)&Bs[kk][tx * 4];
            acc[0][0] += a.x * b.x; acc[0][1] += a.x * b.y; acc[0][2] += a.x * b.z; acc[0][3] += a.x * b.w;
            acc[1][0] += a.y * b.x; acc[1][1] += a.y * b.y; acc[1][2] += a.y * b.z; acc[1][3] += a.y * b.w;
            acc[2][0] += a.z * b.x; acc[2][1] += a.z * b.y; acc[2][2] += a.z * b.z; acc[2][3] += a.z * b.w;
            acc[3][0] += a.w * b.x; acc[3][1] += a.w * b.y; acc[3][2] += a.w * b.z; acc[3][3] += a.w * b.w;
        }
        __syncthreads();
    }
    #pragma unroll
    for (int i = 0; i < 4; ++i) {
        int r = bm + ty * 4 + i;
        if (r < M)
            *(float4*)&C[(size_t)r * N + bn + tx * 4] =
                make_float4(acc[i][0], acc[i][1], acc[i][2], acc[i][3]);
    }
}

// ---------------------------------------------------------------------------
// Per-node attention logits: asrc[n,h] = sum_c h[n,h,c]*att_src[h,c]; ditto adst.
// One block (256 threads) per node.
// ---------------------------------------------------------------------------
template <int CH>
__global__ __launch_bounds__(256) void logits_kernel(const float* __restrict__ h,
                                                     const float* __restrict__ att_src,
                                                     const float* __restrict__ att_dst,
                                                     float* __restrict__ asrc,
                                                     float* __restrict__ adst) {
    constexpr int F = 8 * CH;
    __shared__ float ss[F], sd[F];
    const int i = blockIdx.x, t = threadIdx.x;
    for (int f = t; f < F; f += 256) {
        float v = h[(size_t)i * F + f];
        ss[f] = v * att_src[f];
        sd[f] = v * att_dst[f];
    }
    __syncthreads();
    for (int off = CH / 2; off > 0; off >>= 1) {
        for (int f = t; f < F; f += 256) {
            if ((f & (CH - 1)) < off) { ss[f] += ss[f + off]; sd[f] += sd[f + off]; }
        }
        __syncthreads();
    }
    if (t < 8) {
        asrc[(size_t)i * 8 + t] = ss[t * CH];
        adst[(size_t)i * 8 + t] = sd[t * CH];
    }
}

// ---------------------------------------------------------------------------
// Per-dst-node softmax + weighted aggregation + head-mean + bias (+relu).
// One block (256 threads) per node. CH = per-head channels (64 or 32).
// ---------------------------------------------------------------------------
template <int CH, bool RELU>
__global__ __launch_bounds__(256) void aggregate_kernel(const float* __restrict__ h,
                                                        const float* __restrict__ asrc,
                                                        const float* __restrict__ adst,
                                                        const int* __restrict__ row_start,
                                                        const int* __restrict__ csr_src,
                                                        const float* __restrict__ bias,
                                                        float* __restrict__ out) {
    constexpr int F = 8 * CH;
    constexpr int PER = F / 256;  // 2 for CH=64, 1 for CH=32
    __shared__ float s_red[256];
    __shared__ float s_m[8], s_dinv[8], s_adst[8];
    __shared__ float s_full[F];
    const int i = blockIdx.x;
    const int tid = threadIdx.x;
    const int start = row_start[i];
    const int deg = row_start[i + 1] - start;
    if (tid < 8) s_adst[tid] = adst[(size_t)i * 8 + tid];
    __syncthreads();

    const int head = tid >> 5;   // 32 threads per head
    const int lane = tid & 31;

    // per-head max of leaky_relu(asrc[src] + adst[dst])
    float mx = -1e30f;
    for (int k = lane; k < deg; k += 32) {
        int j = csr_src[start + k];
        float e = asrc[j * 8 + head] + s_adst[head];
        e = e > 0.f ? e : 0.2f * e;
        mx = fmaxf(mx, e);
    }
    s_red[tid] = mx;
    __syncthreads();
    #pragma unroll
    for (int off = 16; off > 0; off >>= 1) {
        if (lane < off) s_red[tid] = fmaxf(s_red[tid], s_red[tid + off]);
        __syncthreads();
    }
    if (lane == 0) s_m[head] = s_red[tid];
    __syncthreads();

    // per-head sum of exp
    const float m_h = s_m[head];
    float sm = 0.f;
    for (int k = lane; k < deg; k += 32) {
        int j = csr_src[start + k];
        float e = asrc[j * 8 + head] + s_adst[head];
        e = e > 0.f ? e : 0.2f * e;
        sm += __expf(e - m_h);
    }
    s_red[tid] = sm;
    __syncthreads();
    #pragma unroll
    for (int off = 16; off > 0; off >>= 1) {
        if (lane < off) s_red[tid] += s_red[tid + off];
        __syncthreads();
    }
    if (lane == 0) s_dinv[head] = 1.0f / s_red[tid];
    __syncthreads();

    // weighted accumulate: thread covers flat channels tid (+256)
    float acc[PER];
    int hh[PER];
    float mm[PER], dd[PER], aa[PER];
    #pragma unroll
    for (int p = 0; p < PER; ++p) {
        acc[p] = 0.f;
        int f = tid + p * 256;
        hh[p] = f / CH;
        mm[p] = s_m[hh[p]];
        dd[p] = s_dinv[hh[p]];
        aa[p] = s_adst[hh[p]];
    }
    for (int k = 0; k < deg; ++k) {
        int j = csr_src[start + k];
        const float* hj = h + (size_t)j * F;
        #pragma unroll
        for (int p = 0; p < PER; ++p) {
            float e = asrc[j * 8 + hh[p]] + aa[p];
            e = e > 0.f ? e : 0.2f * e;
            float al = __expf(e - mm[p]) * dd[p];
            acc[p] += al * hj[tid + p * 256];
        }
    }
    #pragma unroll
    for (int p = 0; p < PER; ++p) s_full[tid + p * 256] = acc[p];
    __syncthreads();

    // mean over heads + bias (+relu)
    if (tid < CH) {
        float v = 0.f;
        #pragma unroll
        for (int h8 = 0; h8 < 8; ++h8) v += s_full[h8 * CH + tid];
        v = v * 0.125f + bias[tid];
        if (RELU) v = fmaxf(v, 0.f);
        out[(size_t)i * CH + tid] = v;
    }
}

// ---------------------------------------------------------------------------
// Launch
// ---------------------------------------------------------------------------
extern "C" void kernel_launch(void* const* d_in, const int* in_sizes, int n_in,
                              void* d_out, int out_size, void* d_ws, size_t ws_size,
                              hipStream_t stream) {
    const float* x   = (const float*)d_in[0];
    const int*   ei  = (const int*)d_in[1];
    const float* W1  = (const float*)d_in[2];
    const float* as1 = (const float*)d_in[3];
    const float* ad1 = (const float*)d_in[4];
    const float* b1  = (const float*)d_in[5];
    const float* W2  = (const float*)d_in[6];
    const float* as2 = (const float*)d_in[7];
    const float* ad2 = (const float*)d_in[8];
    const float* b2  = (const float*)d_in[9];
    float* out = (float*)d_out;

    const int n = N_NODES;
    const int e = E_EDGES;

    // workspace layout
    char* w = (char*)d_ws;
    float* h_buf = (float*)w; w += (size_t)n * 512 * 4;   // h1 then reused for h2
    float* y1    = (float*)w; w += (size_t)n * 64 * 4;
    float* asrc  = (float*)w; w += (size_t)n * 8 * 4;
    float* adst  = (float*)w; w += (size_t)n * 8 * 4;
    int* deg       = (int*)w; w += (size_t)n * 4;
    int* row_start = (int*)w; w += (size_t)(n + 1) * 4;
    int* cursor    = (int*)w; w += (size_t)n * 4;
    int* csr_src   = (int*)w; w += (size_t)(e + n) * 4;

    // ---- CSR build (graph identical for both layers) ----
    init_deg_kernel<<<(n + 255) / 256, 256, 0, stream>>>(deg, n);
    count_deg_kernel<<<(e + 255) / 256, 256, 0, stream>>>(ei, e, deg);
    scan_kernel<<<1, 1024, 0, stream>>>(deg, row_start, cursor, n);
    scatter_kernel<<<(e + n + 255) / 256, 256, 0, stream>>>(ei, e, n, cursor, csr_src);

    const int mblocks = (n + 63) / 64;  // 313

    // ---- Layer 1 ----
    gemm_kernel<<<dim3(mblocks, 8), 256, 0, stream>>>(x, W1, h_buf, n, 256, 512);
    logits_kernel<64><<<n, 256, 0, stream>>>(h_buf, as1, ad1, asrc, adst);
    aggregate_kernel<64, true><<<n, 256, 0, stream>>>(h_buf, asrc, adst, row_start,
                                                      csr_src, b1, y1);

    // ---- Layer 2 ----
    gemm_kernel<<<dim3(mblocks, 4), 256, 0, stream>>>(y1, W2, h_buf, n, 64, 256);
    logits_kernel<32><<<n, 256, 0, stream>>>(h_buf, as2, ad2, asrc, adst);
    aggregate_kernel<32, false><<<n, 256, 0, stream>>>(h_buf, asrc, adst, row_start,
                                                       csr_src, b2, out);
}

// Round 2
// 569.840 us; speedup vs baseline: 1.1835x; 1.1835x over previous
//
#include <hip/hip_runtime.h>

// Problem constants (match reference setup_inputs()).
#define N_NODES 20000
#define E_EDGES 640000
// Layer dims: IN=256, H=8, HF=64, OUT=32

// ---------------------------------------------------------------------------
// CSR build: deg init (self-loop counts as 1), count, scan, scatter
// ---------------------------------------------------------------------------
__global__ __launch_bounds__(256) void init_deg_kernel(int* __restrict__ deg, int n) {
    int i = blockIdx.x * 256 + threadIdx.x;
    if (i < n) deg[i] = 1;  // every node gets exactly one self-loop
}

__global__ __launch_bounds__(256) void count_deg_kernel(const int* __restrict__ ei, int e,
                                                        int* __restrict__ deg) {
    int i = blockIdx.x * 256 + threadIdx.x;
    if (i < e) atomicAdd(&deg[ei[e + i]], 1);  // ei[1][i] = dst
}

__global__ __launch_bounds__(1024) void scan_kernel(const int* __restrict__ deg,
                                                    int* __restrict__ row_start,
                                                    int* __restrict__ cursor, int n) {
    __shared__ int wsum[16];
    __shared__ int carry_s;
    const int t = threadIdx.x;
    const int lane = t & 63;
    const int wv = t >> 6;
    int running = 0;
    for (int base = 0; base < n; base += 1024) {
        int idx = base + t;
        int v = (idx < n) ? deg[idx] : 0;
        int x = v;
        #pragma unroll
        for (int off = 1; off < 64; off <<= 1) {
            int y = __shfl_up(x, off, 64);
            if (lane >= off) x += y;
        }
        if (lane == 63) wsum[wv] = x;
        __syncthreads();
        if (wv == 0 && lane < 16) {
            int w = wsum[lane];
            int xx = w;
            #pragma unroll
            for (int off = 1; off < 16; off <<= 1) {
                int y = __shfl_up(xx, off, 64);
                if (lane >= off) xx += y;
            }
            wsum[lane] = xx - w;
            if (lane == 15) carry_s = xx;
        }
        __syncthreads();
        int excl = running + wsum[wv] + (x - v);
        if (idx < n) { row_start[idx] = excl; cursor[idx] = excl; }
        running += carry_s;
        __syncthreads();
    }
    if (t == 0) row_start[n] = running;
}

__global__ __launch_bounds__(256) void scatter_kernel(const int* __restrict__ ei, int e, int n,
                                                      int* __restrict__ cursor,
                                                      int* __restrict__ csr_src) {
    int i = blockIdx.x * 256 + threadIdx.x;
    if (i >= e + n) return;
    int s, d;
    if (i < e) { s = ei[i]; d = ei[e + i]; }
    else       { s = i - e; d = s; }       // self-loop
    int slot = atomicAdd(&cursor[d], 1);
    csr_src[slot] = s;
}

// ---------------------------------------------------------------------------
// fp32 tiled GEMM: C[M,N] = A[M,K] @ B[K,N].  K % 16 == 0, N % 64 == 0.
// ---------------------------------------------------------------------------
__global__ __launch_bounds__(256) void gemm_kernel(const float* __restrict__ A,
                                                   const float* __restrict__ B,
                                                   float* __restrict__ C,
                                                   int M, int K, int N) {
    __shared__ float As[16][68];
    __shared__ float Bs[16][64];
    const int t = threadIdx.x;
    const int bm = blockIdx.x * 64;
    const int bn = blockIdx.y * 64;
    const int tx = t & 15, ty = t >> 4;
    const int arow = t >> 2;
    const int acol4 = (t & 3) * 4;
    const int brow = t >> 4;
    const int bcol4 = (t & 15) * 4;

    float acc[4][4];
    #pragma unroll
    for (int i = 0; i < 4; ++i)
        #pragma unroll
        for (int j = 0; j < 4; ++j) acc[i][j] = 0.f;

    for (int k0 = 0; k0 < K; k0 += 16) {
        float4 av;
        if (bm + arow < M) av = *(const float4*)&A[(size_t)(bm + arow) * K + k0 + acol4];
        else               av = make_float4(0.f, 0.f, 0.f, 0.f);
        float4 bv = *(const float4*)&B[(size_t)(k0 + brow) * N + bn + bcol4];
        As[acol4 + 0][arow] = av.x;
        As[acol4 + 1][arow] = av.y;
        As[acol4 + 2][arow] = av.z;
        As[acol4 + 3][arow] = av.w;
        *(float4*)&Bs[brow][bcol4] = bv;
        __syncthreads();
        #pragma unroll
        for (int kk = 0; kk < 16; ++kk) {
            float4 a = *(const float4*)&As[kk][ty * 4];
            float4 b = *(const float4*)&Bs[kk][tx * 4];
            acc[0][0] += a.x * b.x; acc[0][1] += a.x * b.y; acc[0][2] += a.x * b.z; acc[0][3] += a.x * b.w;
            acc[1][0] += a.y * b.x; acc[1][1] += a.y * b.y; acc[1][2] += a.y * b.z; acc[1][3] += a.y * b.w;
            acc[2][0] += a.z * b.x; acc[2][1] += a.z * b.y; acc[2][2] += a.z * b.z; acc[2][3] += a.z * b.w;
            acc[3][0] += a.w * b.x; acc[3][1] += a.w * b.y; acc[3][2] += a.w * b.z; acc[3][3] += a.w * b.w;
        }
        __syncthreads();
    }
    #pragma unroll
    for (int i = 0; i < 4; ++i) {
        int r = bm + ty * 4 + i;
        if (r < M)
            *(float4*)&C[(size_t)r * N + bn + tx * 4] =
                make_float4(acc[i][0], acc[i][1], acc[i][2], acc[i][3]);
    }
}

// ---------------------------------------------------------------------------
// Per-node attention logits.
// ---------------------------------------------------------------------------
template <int CH>
__global__ __launch_bounds__(256) void logits_kernel(const float* __restrict__ h,
                                                     const float* __restrict__ att_src,
                                                     const float* __restrict__ att_dst,
                                                     float* __restrict__ asrc,
                                                     float* __restrict__ adst) {
    constexpr int F = 8 * CH;
    __shared__ float ss[F], sd[F];
    const int i = blockIdx.x, t = threadIdx.x;
    for (int f = t; f < F; f += 256) {
        float v = h[(size_t)i * F + f];
        ss[f] = v * att_src[f];
        sd[f] = v * att_dst[f];
    }
    __syncthreads();
    for (int off = CH / 2; off > 0; off >>= 1) {
        for (int f = t; f < F; f += 256) {
            if ((f & (CH - 1)) < off) { ss[f] += ss[f + off]; sd[f] += sd[f + off]; }
        }
        __syncthreads();
    }
    if (t < 8) {
        asrc[(size_t)i * 8 + t] = ss[t * CH];
        adst[(size_t)i * 8 + t] = sd[t * CH];
    }
}

// ---------------------------------------------------------------------------
// Per-dst-node softmax + weighted aggregation + head-mean + bias (+relu).
// v2: edge e-values staged in LDS (one exp per (edge,head) total), float2
// gather, unroll-4 for ILP. One block (256 threads) per node.
// ---------------------------------------------------------------------------
template <int CH, bool RELU>
__global__ __launch_bounds__(256) void aggregate_kernel(const float* __restrict__ h,
                                                        const float* __restrict__ asrc,
                                                        const float* __restrict__ adst,
                                                        const int* __restrict__ row_start,
                                                        const int* __restrict__ csr_src,
                                                        const float* __restrict__ bias,
                                                        float* __restrict__ out) {
    constexpr int F = 8 * CH;
    constexpr int MAXD = 512;      // Poisson(32) graph: max deg ~67. Fallback below.
    __shared__ int   s_src[MAXD];
    __shared__ float s_e[MAXD * 9];   // [k][9]: heads at +0..7, pad to dodge banks
    __shared__ float s_m[8], s_dinv[8], s_adst[8];
    __shared__ float s_full[F];
    const int i = blockIdx.x;
    const int tid = threadIdx.x;
    const int start = row_start[i];
    const int deg = row_start[i + 1] - start;
    const int head = tid >> 5;     // 32 threads per head
    const int lane = tid & 31;

    if (tid < 8) s_adst[tid] = adst[(size_t)i * 8 + tid];

    if (deg <= MAXD) {
        // ---- stage src indices ----
        for (int k = tid; k < deg; k += 256) s_src[k] = csr_src[start + k];
        __syncthreads();

        // ---- phase 1: e = leaky(asrc[src] + adst[dst]) into LDS ----
        {
            const int h8 = tid & 7;
            const float ad = s_adst[h8];
            for (int k = tid >> 3; k < deg; k += 32) {
                float e = asrc[(size_t)s_src[k] * 8 + h8] + ad;  // 32B-coalesced per node
                e = e > 0.f ? e : 0.2f * e;
                s_e[k * 9 + h8] = e;
            }
        }
        __syncthreads();

        // ---- phase 2: per-head max, then exp + sum (exp stored in-place) ----
        float mx = -1e30f;
        for (int k = lane; k < deg; k += 32) mx = fmaxf(mx, s_e[k * 9 + head]);
        #pragma unroll
        for (int off = 16; off > 0; off >>= 1) mx = fmaxf(mx, __shfl_down(mx, off, 32));
        if (lane == 0) s_m[head] = mx;
        __syncthreads();
        const float m_h = s_m[head];
        float sm = 0.f;
        for (int k = lane; k < deg; k += 32) {
            float ex = __expf(s_e[k * 9 + head] - m_h);
            s_e[k * 9 + head] = ex;
            sm += ex;
        }
        #pragma unroll
        for (int off = 16; off > 0; off >>= 1) sm += __shfl_down(sm, off, 32);
        if (lane == 0) s_dinv[head] = 1.0f / sm;
        __syncthreads();

        // ---- phase 3: weighted gather-accumulate ----
        // Thread owns contiguous channels; its head == tid>>5 for both CH=64
        // (2 ch/thread) and CH=32 (1 ch/thread).
        if (CH == 64) {
            const int c0 = 2 * tid;
            float acc0 = 0.f, acc1 = 0.f;
            int k = 0;
            for (; k + 3 < deg; k += 4) {
                int j0 = s_src[k], j1 = s_src[k + 1], j2 = s_src[k + 2], j3 = s_src[k + 3];
                float w0 = s_e[(k) * 9 + head];
                float w1 = s_e[(k + 1) * 9 + head];
                float w2 = s_e[(k + 2) * 9 + head];
                float w3 = s_e[(k + 3) * 9 + head];
                float2 v0 = *(const float2*)&h[(size_t)j0 * F + c0];
                float2 v1 = *(const float2*)&h[(size_t)j1 * F + c0];
                float2 v2 = *(const float2*)&h[(size_t)j2 * F + c0];
                float2 v3 = *(const float2*)&h[(size_t)j3 * F + c0];
                acc0 += w0 * v0.x; acc1 += w0 * v0.y;
                acc0 += w1 * v1.x; acc1 += w1 * v1.y;
                acc0 += w2 * v2.x; acc1 += w2 * v2.y;
                acc0 += w3 * v3.x; acc1 += w3 * v3.y;
            }
            for (; k < deg; ++k) {
                int j = s_src[k];
                float w = s_e[k * 9 + head];
                float2 v = *(const float2*)&h[(size_t)j * F + c0];
                acc0 += w * v.x; acc1 += w * v.y;
            }
            const float dinv = s_dinv[head];
            s_full[c0] = acc0 * dinv;
            s_full[c0 + 1] = acc1 * dinv;
        } else {
            const int c0 = tid;
            float acc0 = 0.f;
            int k = 0;
            for (; k + 3 < deg; k += 4) {
                int j0 = s_src[k], j1 = s_src[k + 1], j2 = s_src[k + 2], j3 = s_src[k + 3];
                float w0 = s_e[(k) * 9 + head];
                float w1 = s_e[(k + 1) * 9 + head];
                float w2 = s_e[(k + 2) * 9 + head];
                float w3 = s_e[(k + 3) * 9 + head];
                float v0 = h[(size_t)j0 * F + c0];
                float v1 = h[(size_t)j1 * F + c0];
                float v2 = h[(size_t)j2 * F + c0];
                float v3 = h[(size_t)j3 * F + c0];
                acc0 += w0 * v0 + w1 * v1 + w2 * v2 + w3 * v3;
            }
            for (; k < deg; ++k) {
                acc0 += s_e[k * 9 + head] * h[(size_t)s_src[k] * F + c0];
            }
            s_full[c0] = acc0 * s_dinv[head];
        }
        __syncthreads();
    } else {
        // ---- fallback slow path (deg > MAXD): recompute-based, round-1 logic ----
        float* s_red = s_e;  // alias scratch
        __syncthreads();

        float mx = -1e30f;
        for (int k = lane; k < deg; k += 32) {
            int j = csr_src[start + k];
            float e = asrc[(size_t)j * 8 + head] + s_adst[head];
            e = e > 0.f ? e : 0.2f * e;
            mx = fmaxf(mx, e);
        }
        s_red[tid] = mx;
        __syncthreads();
        #pragma unroll
        for (int off = 16; off > 0; off >>= 1) {
            if (lane < off) s_red[tid] = fmaxf(s_red[tid], s_red[tid + off]);
            __syncthreads();
        }
        if (lane == 0) s_m[head] = s_red[tid];
        __syncthreads();

        const float m_h = s_m[head];
        float sm = 0.f;
        for (int k = lane; k < deg; k += 32) {
            int j = csr_src[start + k];
            float e = asrc[(size_t)j * 8 + head] + s_adst[head];
            e = e > 0.f ? e : 0.2f * e;
            sm += __expf(e - m_h);
        }
        s_red[tid] = sm;
        __syncthreads();
        #pragma unroll
        for (int off = 16; off > 0; off >>= 1) {
            if (lane < off) s_red[tid] += s_red[tid + off];
            __syncthreads();
        }
        if (lane == 0) s_dinv[head] = 1.0f / s_red[tid];
        __syncthreads();

        constexpr int PER = F / 256;
        float acc[PER];
        int hh[PER];
        float mm[PER], dd[PER], aa[PER];
        #pragma unroll
        for (int p = 0; p < PER; ++p) {
            acc[p] = 0.f;
            int f = tid + p * 256;
            hh[p] = f / CH;
            mm[p] = s_m[hh[p]];
            dd[p] = s_dinv[hh[p]];
            aa[p] = s_adst[hh[p]];
        }
        for (int k = 0; k < deg; ++k) {
            int j = csr_src[start + k];
            const float* hj = h + (size_t)j * F;
            #pragma unroll
            for (int p = 0; p < PER; ++p) {
                float e = asrc[(size_t)j * 8 + hh[p]] + aa[p];
                e = e > 0.f ? e : 0.2f * e;
                float al = __expf(e - mm[p]) * dd[p];
                acc[p] += al * hj[tid + p * 256];
            }
        }
        #pragma unroll
        for (int p = 0; p < PER; ++p) s_full[tid + p * 256] = acc[p];
        __syncthreads();
    }

    // ---- mean over heads + bias (+relu) ----
    if (tid < CH) {
        float v = 0.f;
        #pragma unroll
        for (int h8 = 0; h8 < 8; ++h8) v += s_full[h8 * CH + tid];
        v = v * 0.125f + bias[tid];
        if (RELU) v = fmaxf(v, 0.f);
        out[(size_t)i * CH + tid] = v;
    }
}

// ---------------------------------------------------------------------------
// Launch
// ---------------------------------------------------------------------------
extern "C" void kernel_launch(void* const* d_in, const int* in_sizes, int n_in,
                              void* d_out, int out_size, void* d_ws, size_t ws_size,
                              hipStream_t stream) {
    const float* x   = (const float*)d_in[0];
    const int*   ei  = (const int*)d_in[1];
    const float* W1  = (const float*)d_in[2];
    const float* as1 = (const float*)d_in[3];
    const float* ad1 = (const float*)d_in[4];
    const float* b1  = (const float*)d_in[5];
    const float* W2  = (const float*)d_in[6];
    const float* as2 = (const float*)d_in[7];
    const float* ad2 = (const float*)d_in[8];
    const float* b2  = (const float*)d_in[9];
    float* out = (float*)d_out;

    const int n = N_NODES;
    const int e = E_EDGES;

    // workspace layout
    char* w = (char*)d_ws;
    float* h_buf = (float*)w; w += (size_t)n * 512 * 4;   // h1 then reused for h2
    float* y1    = (float*)w; w += (size_t)n * 64 * 4;
    float* asrc  = (float*)w; w += (size_t)n * 8 * 4;
    float* adst  = (float*)w; w += (size_t)n * 8 * 4;
    int* deg       = (int*)w; w += (size_t)n * 4;
    int* row_start = (int*)w; w += (size_t)(n + 1) * 4;
    int* cursor    = (int*)w; w += (size_t)n * 4;
    int* csr_src   = (int*)w; w += (size_t)(e + n) * 4;

    // ---- CSR build (graph identical for both layers) ----
    init_deg_kernel<<<(n + 255) / 256, 256, 0, stream>>>(deg, n);
    count_deg_kernel<<<(e + 255) / 256, 256, 0, stream>>>(ei, e, deg);
    scan_kernel<<<1, 1024, 0, stream>>>(deg, row_start, cursor, n);
    scatter_kernel<<<(e + n + 255) / 256, 256, 0, stream>>>(ei, e, n, cursor, csr_src);

    const int mblocks = (n + 63) / 64;  // 313

    // ---- Layer 1 ----
    gemm_kernel<<<dim3(mblocks, 8), 256, 0, stream>>>(x, W1, h_buf, n, 256, 512);
    logits_kernel<64><<<n, 256, 0, stream>>>(h_buf, as1, ad1, asrc, adst);
    aggregate_kernel<64, true><<<n, 256, 0, stream>>>(h_buf, asrc, adst, row_start,
                                                      csr_src, b1, y1);

    // ---- Layer 2 ----
    gemm_kernel<<<dim3(mblocks, 4), 256, 0, stream>>>(y1, W2, h_buf, n, 64, 256);
    logits_kernel<32><<<n, 256, 0, stream>>>(h_buf, as2, ad2, asrc, adst);
    aggregate_kernel<32, false><<<n, 256, 0, stream>>>(h_buf, asrc, adst, row_start,
                                                       csr_src, b2, out);
}